// Round 5
// baseline (208.100 us; speedup 1.0000x reference)
//
#include <hip/hip_runtime.h>
#include <math.h>

#define NN 4096
#define DD 512
#define NC 10
#define NG 2

#define BM 128
#define BN 128
#define BK 32
#define NT (DD / BK)   // 16 K-steps

typedef __bf16 bf16x8 __attribute__((ext_vector_type(8)));
typedef __bf16 bf16x4 __attribute__((ext_vector_type(4)));
typedef float f32x4 __attribute__((ext_vector_type(4)));

__device__ __forceinline__ void load_lds16(const __bf16* g, __bf16* l) {
    __builtin_amdgcn_global_load_lds((const __attribute__((address_space(1))) void*)g,
                                     (__attribute__((address_space(3))) void*)l, 16, 0, 0);
}

// ---------------------------------------------------------------------------
// Kernel 1: fused fp32->bf16 convert + per-row squared norms (fp32 exact).
// ---------------------------------------------------------------------------
__global__ void k_prep(const float* __restrict__ ft, const float* __restrict__ fs,
                       __bf16* __restrict__ at, __bf16* __restrict__ as_,
                       float* __restrict__ nt, float* __restrict__ ns) {
    int wid  = threadIdx.x >> 6;
    int lane = threadIdx.x & 63;
    int r = blockIdx.x * 4 + wid;
    const float* src; __bf16* bdst; float* ndst; int row;
    if (r < NN) { src = ft; bdst = at;  ndst = nt; row = r; }
    else        { src = fs; bdst = as_; ndst = ns; row = r - NN; }
    const float4* p = (const float4*)(src + (size_t)row * DD);
    float s = 0.0f;
#pragma unroll
    for (int c = 0; c < 2; ++c) {
        float4 v = p[lane + 64 * c];
        s += v.x * v.x + v.y * v.y + v.z * v.z + v.w * v.w;
        bf16x4 b;
        b[0] = (__bf16)v.x; b[1] = (__bf16)v.y; b[2] = (__bf16)v.z; b[3] = (__bf16)v.w;
        *(bf16x4*)(bdst + (size_t)row * DD + (lane + 64 * c) * 4) = b;
    }
#pragma unroll
    for (int o = 32; o; o >>= 1) s += __shfl_xor(s, o);
    if (lane == 0) ndst[row] = s;
}

// ---------------------------------------------------------------------------
// Kernel 2: column sums (fp32 inputs, for closed-form sigma).
// ---------------------------------------------------------------------------
__global__ void k_colsums(const float* __restrict__ ft, const float* __restrict__ fs,
                          float* __restrict__ sumT, float* __restrict__ sumS) {
    int b = blockIdx.x;
    int mat = b & 1;
    int chunk = b >> 1;
    const float* src = mat ? fs : ft;
    float* dst = mat ? sumS : sumT;
    int r0 = chunk * 32;
    int c0 = threadIdx.x, c1 = threadIdx.x + 256;
    float a0 = 0.0f, a1 = 0.0f;
    for (int r = r0; r < r0 + 32; ++r) {
        a0 += src[(size_t)r * DD + c0];
        a1 += src[(size_t)r * DD + c1];
    }
    atomicAdd(&dst[c0], a0);
    atomicAdd(&dst[c1], a1);
}

// ---------------------------------------------------------------------------
// Kernel 3: inv_scale = 1/(2*sigma_avg), sigma closed form.
// ---------------------------------------------------------------------------
__global__ void k_scale(const float* __restrict__ nt, const float* __restrict__ ns,
                        const float* __restrict__ sumT, const float* __restrict__ sumS,
                        float* __restrict__ invscale) {
    __shared__ float red[8];
    int tid = threadIdx.x;
    float s = 0.0f;
    for (int i = tid; i < NN; i += 256) s += nt[i] + ns[i];
    float d = 0.0f;
    for (int i = tid; i < DD; i += 256) d += sumT[i] * sumS[i];
#pragma unroll
    for (int o = 32; o; o >>= 1) { s += __shfl_xor(s, o); d += __shfl_xor(d, o); }
    int wid = tid >> 6, lane = tid & 63;
    if (lane == 0) { red[wid] = s; red[wid + 4] = d; }
    __syncthreads();
    if (tid == 0) {
        float S  = red[0] + red[1] + red[2] + red[3];
        float Dt = red[4] + red[5] + red[6] + red[7];
        float sigma = S / (float)NN - 2.0f * Dt / ((float)NN * (float)NN);
        invscale[0] = 1.0f / (2.0f * sigma);
    }
}

// ---------------------------------------------------------------------------
// Kernel 4: all three Grams in one launch (blockIdx.z = mode).
// mode 0 = TT (label match), 1 = SS (label&&group), 2 = TS (split by grpB).
// 128x128 tile, 4 waves (2x2), wave tile 64x64 via 4x4 mfma_f32_16x16x32_bf16.
// TRIPLE-buffered LDS (48 KB), depth-2 prefetch, counted s_waitcnt vmcnt(N)
// + raw s_barrier (T4): loads for tile t+1/t+2 stay in flight across barriers;
// the barrier never drains the deep prefetch. 4 global_load_lds per thread per
// tile -> steady wait vmcnt(4).
// LDS per buffer: [q=k/8][row=128][8] bf16; conflict-free ds_read_b128.
// ---------------------------------------------------------------------------
__global__ __launch_bounds__(256, 3) void k_gram_all(
    const __bf16* __restrict__ T, const __bf16* __restrict__ S,
    const float* __restrict__ nt, const float* __restrict__ ns,
    const int* __restrict__ labels, const int* __restrict__ groups,
    const float* __restrict__ invscale_p,
    float* __restrict__ zTT, float* __restrict__ zSS, float* __restrict__ zTS) {

    __shared__ __bf16 As[3][4 * 128 * 8];
    __shared__ __bf16 Bs[3][4 * 128 * 8];

    int mode = blockIdx.z;
    const __bf16* A = (mode == 1) ? S : T;
    const __bf16* B = (mode == 0) ? T : S;
    const float* nA = (mode == 1) ? ns : nt;
    const float* nB = (mode == 0) ? nt : ns;
    float* z0 = (mode == 0) ? zTT : ((mode == 1) ? zSS : zTS);
    float* z1 = zTS + NN;

    int tid = threadIdx.x;
    int i0 = blockIdx.y * BM;
    int j0 = blockIdx.x * BN;

    int lane = tid & 63, wid = tid >> 6;
    int wr = wid >> 1, wc = wid & 1;          // 2 x 2 wave grid
    int l15 = lane & 15, l4 = lane >> 4;

    // staging: per thread 2 A-slots + 2 B-slots per tile.
    // slot s = tid (+256): row = tid&127, q = tid>>7 (and +2)
    int sr = tid & 127;
    int q0 = tid >> 7;                        // 0..1
    const __bf16* gA = A + (size_t)(i0 + sr) * DD + q0 * 8;   // +16 elems = chunk q0+2
    const __bf16* gB = B + (size_t)(j0 + sr) * DD + q0 * 8;

    f32x4 acc[4][4] = {};

#define STAGE(bb, tt)                                                          \
    do {                                                                       \
        int _k0 = (tt) * BK;                                                   \
        load_lds16(gA + _k0,      &As[(bb)][(size_t)tid * 8]);                 \
        load_lds16(gA + _k0 + 16, &As[(bb)][(size_t)(tid + 256) * 8]);         \
        load_lds16(gB + _k0,      &Bs[(bb)][(size_t)tid * 8]);                 \
        load_lds16(gB + _k0 + 16, &Bs[(bb)][(size_t)(tid + 256) * 8]);         \
    } while (0)

    // prologue: stage tiles 0,1 -> bufs 0,1; wait tile0 (keep tile1 in flight)
    STAGE(0, 0);
    STAGE(1, 1);
    asm volatile("s_waitcnt vmcnt(4)" ::: "memory");
    __builtin_amdgcn_s_barrier();
    __builtin_amdgcn_sched_barrier(0);

#pragma unroll
    for (int t = 0; t < NT; ++t) {
        int b = t % 3;
        // ds_read current tile fragments (compiler inserts lgkmcnt before MFMA use)
        bf16x8 af[4], bfr[4];
#pragma unroll
        for (int im = 0; im < 4; ++im)
            af[im] = *(const bf16x8*)&As[b][((size_t)l4 * 128 + wr * 64 + im * 16 + l15) * 8];
#pragma unroll
        for (int in = 0; in < 4; ++in)
            bfr[in] = *(const bf16x8*)&Bs[b][((size_t)l4 * 128 + wc * 64 + in * 16 + l15) * 8];
        // stage tile t+2 into the buffer freed at step t-1
        if (t + 2 < NT) STAGE((t + 2) % 3, t + 2);
        // MFMA on current tile
#pragma unroll
        for (int im = 0; im < 4; ++im)
#pragma unroll
            for (int in = 0; in < 4; ++in)
                acc[im][in] = __builtin_amdgcn_mfma_f32_16x16x32_bf16(af[im], bfr[in], acc[im][in], 0, 0, 0);
        // end of step: require tile t+1 resident; keep tile t+2's loads in flight
        if (t + 1 < NT) {
            if (t + 2 < NT) asm volatile("s_waitcnt vmcnt(4)" ::: "memory");
            else            asm volatile("s_waitcnt vmcnt(0)" ::: "memory");
            __builtin_amdgcn_s_barrier();
            __builtin_amdgcn_sched_barrier(0);
        }
    }
#undef STAGE

    // epilogue: D = nA + nB - 2*dot -> exp -> predicate -> per-row sums
    float inv_scale = invscale_p[0];
    int ibase = i0 + wr * 64;
    int jbase = j0 + wc * 64;
    float nBv[4];
    int labBv[4], grpBv[4];
#pragma unroll
    for (int in = 0; in < 4; ++in) {
        int j = jbase + in * 16 + l15;
        nBv[in] = nB[j];
        labBv[in] = labels[j];
        grpBv[in] = groups[j];
    }
#pragma unroll
    for (int im = 0; im < 4; ++im) {
#pragma unroll
        for (int j = 0; j < 4; ++j) {
            int row = ibase + im * 16 + l4 * 4 + j;
            float ni = nA[row];
            int li = labels[row];
            int gi = groups[row];
            float s0 = 0.0f, s1 = 0.0f;
#pragma unroll
            for (int in = 0; in < 4; ++in) {
                float d = ni + nBv[in] - 2.0f * acc[im][in][j];
                d = fmaxf(d, 1e-12f);
                float kv = __expf(-d * inv_scale);
                bool ok = (li == labBv[in]);
                if (mode == 1) ok = ok && (gi == grpBv[in]);
                if (mode == 2) {
                    s0 += (ok && grpBv[in] == 0) ? kv : 0.0f;
                    s1 += (ok && grpBv[in] == 1) ? kv : 0.0f;
                } else {
                    s0 += ok ? kv : 0.0f;
                }
            }
#pragma unroll
            for (int o = 1; o < 16; o <<= 1) {
                s0 += __shfl_xor(s0, o);
                if (mode == 2) s1 += __shfl_xor(s1, o);
            }
            if (l15 == 0) {
                atomicAdd(&z0[row], s0);
                if (mode == 2) atomicAdd(&z1[row], s1);
            }
        }
    }
}

// ---------------------------------------------------------------------------
// Kernel 5: bucket per-row sums, final scalar.
// ---------------------------------------------------------------------------
__global__ void k_final(const int* __restrict__ labels, const int* __restrict__ groups,
                        const float* __restrict__ zTT, const float* __restrict__ zSS,
                        const float* __restrict__ zTS, float* __restrict__ out) {
    __shared__ float cnt_t[NC], cnt_s[NC * NG];
    __shared__ float nTT[NC], nSS[NC * NG], nTS[NC * NG];
    int tid = threadIdx.x;
    if (tid < NC) { cnt_t[tid] = 0.0f; nTT[tid] = 0.0f; }
    if (tid < NC * NG) { cnt_s[tid] = 0.0f; nSS[tid] = 0.0f; nTS[tid] = 0.0f; }
    __syncthreads();
    for (int i = tid; i < NN; i += 256) {
        int l = labels[i], g = groups[i];
        atomicAdd(&cnt_t[l], 1.0f);
        atomicAdd(&cnt_s[l * NG + g], 1.0f);
        atomicAdd(&nTT[l], zTT[i]);
        atomicAdd(&nSS[l * NG + g], zSS[i]);
        atomicAdd(&nTS[l * NG + 0], zTS[i]);
        atomicAdd(&nTS[l * NG + 1], zTS[NN + i]);
    }
    __syncthreads();
    if (tid == 0) {
        float total = 0.0f;
        for (int c = 0; c < NC; ++c) {
            float ntc = cnt_t[c];
            float sn = fmaxf(ntc, 1.0f);
            float meanTT = nTT[c] / (sn * sn);
            for (int g = 0; g < NG; ++g) {
                float nsg = cnt_s[c * NG + g];
                float ss = fmaxf(nsg, 1.0f);
                float meanSS = nSS[c * NG + g] / (ss * ss);
                float meanTS = nTS[c * NG + g] / (sn * ss);
                if (ntc > 0.0f && nsg > 0.0f)
                    total += meanTT + meanSS - 2.0f * meanTS;
            }
        }
        out[0] = 0.5f * total;
    }
}

// ---------------------------------------------------------------------------
// workspace layout:
// bytes [0, 4MB)      : teacher bf16 [4096][512]
// bytes [4MB, 8MB)    : student bf16 [4096][512]
// floats from 8MB:
//   +0      nt[4096]
//   +4096   ns[4096]
//   +8192   sumT[512]      <- zero region start
//   +8704   sumS[512]
//   +9216   zTT[4096]
//   +13312  zSS[4096]
//   +17408  zTS[2*4096]
//   +25600  invscale[1]    <- zero region end
// ---------------------------------------------------------------------------
extern "C" void kernel_launch(void* const* d_in, const int* in_sizes, int n_in,
                              void* d_out, int out_size, void* d_ws, size_t ws_size,
                              hipStream_t stream) {
    const float* fs     = (const float*)d_in[0];
    const float* ft     = (const float*)d_in[1];
    const int*   groups = (const int*)d_in[2];
    const int*   labels = (const int*)d_in[3];

    __bf16* Abf = (__bf16*)d_ws;                       // teacher
    __bf16* Bbf = (__bf16*)d_ws + (size_t)NN * DD;     // student
    float* wsf  = (float*)((char*)d_ws + (size_t)2 * NN * DD * sizeof(__bf16));
    float* nt   = wsf;
    float* ns   = wsf + 4096;
    float* sumT = wsf + 8192;
    float* sumS = wsf + 8704;
    float* zTT  = wsf + 9216;
    float* zSS  = wsf + 13312;
    float* zTS  = wsf + 17408;
    float* invs = wsf + 25600;

    hipMemsetAsync(wsf + 8192, 0, (size_t)17408 * sizeof(float), stream);

    k_prep<<<2048, 256, 0, stream>>>(ft, fs, Abf, Bbf, nt, ns);
    k_colsums<<<256, 256, 0, stream>>>(ft, fs, sumT, sumS);
    k_scale<<<1, 256, 0, stream>>>(nt, ns, sumT, sumS, invs);

    dim3 grid(NN / BN, NN / BM, 3);
    k_gram_all<<<grid, 256, 0, stream>>>(Abf, Bbf, nt, ns, labels, groups,
                                         invs, zTT, zSS, zTS);

    k_final<<<1, 256, 0, stream>>>(labels, groups, zTT, zSS, zTS, (float*)d_out);
}

// Round 6
// 181.926 us; speedup vs baseline: 1.1439x; 1.1439x over previous
//
#include <hip/hip_runtime.h>
#include <math.h>

#define NN 4096
#define DD 512
#define NC 10
#define NG 2

#define BM 256
#define BN 128
#define BK 32
#define NT (DD / BK)   // 16 K-steps

typedef __bf16 bf16x8 __attribute__((ext_vector_type(8)));
typedef __bf16 bf16x4 __attribute__((ext_vector_type(4)));
typedef float f32x4 __attribute__((ext_vector_type(4)));

__device__ __forceinline__ void load_lds16(const __bf16* g, __bf16* l) {
    __builtin_amdgcn_global_load_lds((const __attribute__((address_space(1))) void*)g,
                                     (__attribute__((address_space(3))) void*)l, 16, 0, 0);
}

// ---------------------------------------------------------------------------
// Kernel 1: fused fp32->bf16 convert + per-row squared norms (fp32 exact).
// ---------------------------------------------------------------------------
__global__ void k_prep(const float* __restrict__ ft, const float* __restrict__ fs,
                       __bf16* __restrict__ at, __bf16* __restrict__ as_,
                       float* __restrict__ nt, float* __restrict__ ns) {
    int wid  = threadIdx.x >> 6;
    int lane = threadIdx.x & 63;
    int r = blockIdx.x * 4 + wid;
    const float* src; __bf16* bdst; float* ndst; int row;
    if (r < NN) { src = ft; bdst = at;  ndst = nt; row = r; }
    else        { src = fs; bdst = as_; ndst = ns; row = r - NN; }
    const float4* p = (const float4*)(src + (size_t)row * DD);
    float s = 0.0f;
#pragma unroll
    for (int c = 0; c < 2; ++c) {
        float4 v = p[lane + 64 * c];
        s += v.x * v.x + v.y * v.y + v.z * v.z + v.w * v.w;
        bf16x4 b;
        b[0] = (__bf16)v.x; b[1] = (__bf16)v.y; b[2] = (__bf16)v.z; b[3] = (__bf16)v.w;
        *(bf16x4*)(bdst + (size_t)row * DD + (lane + 64 * c) * 4) = b;
    }
#pragma unroll
    for (int o = 32; o; o >>= 1) s += __shfl_xor(s, o);
    if (lane == 0) ndst[row] = s;
}

// ---------------------------------------------------------------------------
// Kernel 2: column sums (fp32 inputs, for closed-form sigma).
// ---------------------------------------------------------------------------
__global__ void k_colsums(const float* __restrict__ ft, const float* __restrict__ fs,
                          float* __restrict__ sumT, float* __restrict__ sumS) {
    int b = blockIdx.x;
    int mat = b & 1;
    int chunk = b >> 1;
    const float* src = mat ? fs : ft;
    float* dst = mat ? sumS : sumT;
    int r0 = chunk * 32;
    int c0 = threadIdx.x, c1 = threadIdx.x + 256;
    float a0 = 0.0f, a1 = 0.0f;
    for (int r = r0; r < r0 + 32; ++r) {
        a0 += src[(size_t)r * DD + c0];
        a1 += src[(size_t)r * DD + c1];
    }
    atomicAdd(&dst[c0], a0);
    atomicAdd(&dst[c1], a1);
}

// ---------------------------------------------------------------------------
// Kernel 3: inv_scale = 1/(2*sigma_avg), sigma closed form.
// ---------------------------------------------------------------------------
__global__ void k_scale(const float* __restrict__ nt, const float* __restrict__ ns,
                        const float* __restrict__ sumT, const float* __restrict__ sumS,
                        float* __restrict__ invscale) {
    __shared__ float red[8];
    int tid = threadIdx.x;
    float s = 0.0f;
    for (int i = tid; i < NN; i += 256) s += nt[i] + ns[i];
    float d = 0.0f;
    for (int i = tid; i < DD; i += 256) d += sumT[i] * sumS[i];
#pragma unroll
    for (int o = 32; o; o >>= 1) { s += __shfl_xor(s, o); d += __shfl_xor(d, o); }
    int wid = tid >> 6, lane = tid & 63;
    if (lane == 0) { red[wid] = s; red[wid + 4] = d; }
    __syncthreads();
    if (tid == 0) {
        float S  = red[0] + red[1] + red[2] + red[3];
        float Dt = red[4] + red[5] + red[6] + red[7];
        float sigma = S / (float)NN - 2.0f * Dt / ((float)NN * (float)NN);
        invscale[0] = 1.0f / (2.0f * sigma);
    }
}

// ---------------------------------------------------------------------------
// Kernel 4: all three Grams, 1D grid with symmetric-triangle elimination.
// blocks [0,272)   : TT upper-triangle blocks (bj >= 2*bi)
// blocks [272,544) : SS upper-triangle blocks
// blocks [544,1056): TS full grid (16 x 32)
// 256x128 tile, 8 waves (4Mx2N), wave tile 64x64, BK=32, double-buffered LDS
// stage-ahead + drain barrier (round-4 structure; best measured).
// Sym modes: element rule c>r -> row+col add; c==r -> row add; c<r -> skip.
// Each unordered pair is covered exactly once across the triangular grid.
// ---------------------------------------------------------------------------
__global__ __launch_bounds__(512, 4) void k_gram_all(
    const __bf16* __restrict__ T, const __bf16* __restrict__ S,
    const float* __restrict__ nt, const float* __restrict__ ns,
    const int* __restrict__ labels, const int* __restrict__ groups,
    const float* __restrict__ invscale_p,
    float* __restrict__ zTT, float* __restrict__ zSS, float* __restrict__ zTS) {

    __shared__ __bf16 As[2][4 * 256 * 8];
    __shared__ __bf16 Bs[2][4 * 128 * 8];

    int id = blockIdx.x;
    int mode, bi, bj;
    if (id < 544) {
        mode = (id < 272) ? 0 : 1;
        int k = (id < 272) ? id : id - 272;
        int t = 0;
        while (k >= 32 - 2 * t) { k -= 32 - 2 * t; ++t; }   // uniform, <=16 iters
        bi = t; bj = 2 * t + k;
    } else {
        mode = 2;
        int k = id - 544;
        bi = k >> 5; bj = k & 31;
    }

    const __bf16* A = (mode == 1) ? S : T;
    const __bf16* B = (mode == 0) ? T : S;
    const float* nA = (mode == 1) ? ns : nt;
    const float* nB = (mode == 0) ? nt : ns;
    float* z0 = (mode == 0) ? zTT : ((mode == 1) ? zSS : zTS);
    float* z1 = zTS + NN;

    int tid = threadIdx.x;
    int i0 = bi * BM;
    int j0 = bj * BN;

    int lane = tid & 63, wid = tid >> 6;
    int wr = wid >> 1, wc = wid & 1;          // 4 x 2 wave grid
    int l15 = lane & 15, l4 = lane >> 4;

    // staging: A slots tid, tid+512 (row=tid&255, q=tid>>8 and +2); B slot tid.
    int ra = tid & 255;
    int qa = tid >> 8;                        // 0..1
    int rb = tid & 127;
    int qb = tid >> 7;                        // 0..3
    const __bf16* gA = A + (size_t)(i0 + ra) * DD + qa * 8;   // +16 = chunk qa+2
    const __bf16* gB = B + (size_t)(j0 + rb) * DD + qb * 8;

    f32x4 acc[4][4] = {};

    // prologue: stage tile 0 into buf 0
    load_lds16(gA,      &As[0][(size_t)tid * 8]);
    load_lds16(gA + 16, &As[0][(size_t)(tid + 512) * 8]);
    load_lds16(gB,      &Bs[0][(size_t)tid * 8]);
    __syncthreads();

#pragma unroll 2
    for (int t = 0; t < NT; ++t) {
        int b = t & 1;
        if (t < NT - 1) {
            int k0 = (t + 1) * BK;
            load_lds16(gA + k0,      &As[b ^ 1][(size_t)tid * 8]);
            load_lds16(gA + k0 + 16, &As[b ^ 1][(size_t)(tid + 512) * 8]);
            load_lds16(gB + k0,      &Bs[b ^ 1][(size_t)tid * 8]);
        }
        bf16x8 af[4], bfr[4];
#pragma unroll
        for (int im = 0; im < 4; ++im)
            af[im] = *(const bf16x8*)&As[b][((size_t)l4 * 256 + wr * 64 + im * 16 + l15) * 8];
#pragma unroll
        for (int in = 0; in < 4; ++in)
            bfr[in] = *(const bf16x8*)&Bs[b][((size_t)l4 * 128 + wc * 64 + in * 16 + l15) * 8];
#pragma unroll
        for (int im = 0; im < 4; ++im)
#pragma unroll
            for (int in = 0; in < 4; ++in)
                acc[im][in] = __builtin_amdgcn_mfma_f32_16x16x32_bf16(af[im], bfr[in], acc[im][in], 0, 0, 0);
        __syncthreads();   // next tile staged + buffer reuse protected
    }

    // epilogue: D = nA + nB - 2*dot -> exp -> predicate -> row/col sums
    float inv_scale = invscale_p[0];
    int ibase = i0 + wr * 64;
    int jbase = j0 + wc * 64;
    float nBv[4];
    int labBv[4], grpBv[4];
#pragma unroll
    for (int in = 0; in < 4; ++in) {
        int j = jbase + in * 16 + l15;
        nBv[in] = nB[j];
        labBv[in] = labels[j];
        grpBv[in] = groups[j];
    }
    float cs[4] = {0.0f, 0.0f, 0.0f, 0.0f};   // sym col sums (c > r)
#pragma unroll
    for (int im = 0; im < 4; ++im) {
#pragma unroll
        for (int j = 0; j < 4; ++j) {
            int row = ibase + im * 16 + l4 * 4 + j;
            float ni = nA[row];
            int li = labels[row];
            int gi = groups[row];
            float s0 = 0.0f, s1 = 0.0f;
#pragma unroll
            for (int in = 0; in < 4; ++in) {
                float d = ni + nBv[in] - 2.0f * acc[im][in][j];
                d = fmaxf(d, 1e-12f);
                float kv = __expf(-d * inv_scale);
                bool ok = (li == labBv[in]);
                if (mode == 1) ok = ok && (gi == grpBv[in]);
                if (mode == 2) {
                    s0 += (ok && grpBv[in] == 0) ? kv : 0.0f;
                    s1 += (ok && grpBv[in] == 1) ? kv : 0.0f;
                } else {
                    int c = jbase + in * 16 + l15;
                    s0     += (ok && c >= row) ? kv : 0.0f;
                    cs[in] += (ok && c >  row) ? kv : 0.0f;
                }
            }
#pragma unroll
            for (int o = 1; o < 16; o <<= 1) {
                s0 += __shfl_xor(s0, o);
                if (mode == 2) s1 += __shfl_xor(s1, o);
            }
            if (l15 == 0) {
                atomicAdd(&z0[row], s0);
                if (mode == 2) atomicAdd(&z1[row], s1);
            }
        }
    }
    if (mode != 2) {
        // reduce col sums across the 4 l4 groups (lanes xor 16, 32)
#pragma unroll
        for (int in = 0; in < 4; ++in) {
            cs[in] += __shfl_xor(cs[in], 16);
            cs[in] += __shfl_xor(cs[in], 32);
        }
        if (l4 == 0) {
#pragma unroll
            for (int in = 0; in < 4; ++in)
                atomicAdd(&z0[jbase + in * 16 + l15], cs[in]);
        }
    }
}

// ---------------------------------------------------------------------------
// Kernel 5: bucket per-row sums, final scalar.
// ---------------------------------------------------------------------------
__global__ void k_final(const int* __restrict__ labels, const int* __restrict__ groups,
                        const float* __restrict__ zTT, const float* __restrict__ zSS,
                        const float* __restrict__ zTS, float* __restrict__ out) {
    __shared__ float cnt_t[NC], cnt_s[NC * NG];
    __shared__ float nTT[NC], nSS[NC * NG], nTS[NC * NG];
    int tid = threadIdx.x;
    if (tid < NC) { cnt_t[tid] = 0.0f; nTT[tid] = 0.0f; }
    if (tid < NC * NG) { cnt_s[tid] = 0.0f; nSS[tid] = 0.0f; nTS[tid] = 0.0f; }
    __syncthreads();
    for (int i = tid; i < NN; i += 256) {
        int l = labels[i], g = groups[i];
        atomicAdd(&cnt_t[l], 1.0f);
        atomicAdd(&cnt_s[l * NG + g], 1.0f);
        atomicAdd(&nTT[l], zTT[i]);
        atomicAdd(&nSS[l * NG + g], zSS[i]);
        atomicAdd(&nTS[l * NG + 0], zTS[i]);
        atomicAdd(&nTS[l * NG + 1], zTS[NN + i]);
    }
    __syncthreads();
    if (tid == 0) {
        float total = 0.0f;
        for (int c = 0; c < NC; ++c) {
            float ntc = cnt_t[c];
            float sn = fmaxf(ntc, 1.0f);
            float meanTT = nTT[c] / (sn * sn);
            for (int g = 0; g < NG; ++g) {
                float nsg = cnt_s[c * NG + g];
                float ss = fmaxf(nsg, 1.0f);
                float meanSS = nSS[c * NG + g] / (ss * ss);
                float meanTS = nTS[c * NG + g] / (sn * ss);
                if (ntc > 0.0f && nsg > 0.0f)
                    total += meanTT + meanSS - 2.0f * meanTS;
            }
        }
        out[0] = 0.5f * total;
    }
}

// ---------------------------------------------------------------------------
// workspace layout:
// bytes [0, 4MB)      : teacher bf16 [4096][512]
// bytes [4MB, 8MB)    : student bf16 [4096][512]
// floats from 8MB:
//   +0      nt[4096]
//   +4096   ns[4096]
//   +8192   sumT[512]      <- zero region start
//   +8704   sumS[512]
//   +9216   zTT[4096]
//   +13312  zSS[4096]
//   +17408  zTS[2*4096]
//   +25600  invscale[1]    <- zero region end
// ---------------------------------------------------------------------------
extern "C" void kernel_launch(void* const* d_in, const int* in_sizes, int n_in,
                              void* d_out, int out_size, void* d_ws, size_t ws_size,
                              hipStream_t stream) {
    const float* fs     = (const float*)d_in[0];
    const float* ft     = (const float*)d_in[1];
    const int*   groups = (const int*)d_in[2];
    const int*   labels = (const int*)d_in[3];

    __bf16* Abf = (__bf16*)d_ws;                       // teacher
    __bf16* Bbf = (__bf16*)d_ws + (size_t)NN * DD;     // student
    float* wsf  = (float*)((char*)d_ws + (size_t)2 * NN * DD * sizeof(__bf16));
    float* nt   = wsf;
    float* ns   = wsf + 4096;
    float* sumT = wsf + 8192;
    float* sumS = wsf + 8704;
    float* zTT  = wsf + 9216;
    float* zSS  = wsf + 13312;
    float* zTS  = wsf + 17408;
    float* invs = wsf + 25600;

    hipMemsetAsync(wsf + 8192, 0, (size_t)17408 * sizeof(float), stream);

    k_prep<<<2048, 256, 0, stream>>>(ft, fs, Abf, Bbf, nt, ns);
    k_colsums<<<256, 256, 0, stream>>>(ft, fs, sumT, sumS);
    k_scale<<<1, 256, 0, stream>>>(nt, ns, sumT, sumS, invs);

    k_gram_all<<<1056, 512, 0, stream>>>(Abf, Bbf, nt, ns, labels, groups,
                                         invs, zTT, zSS, zTS);

    k_final<<<1, 256, 0, stream>>>(labels, groups, zTT, zSS, zTS, (float*)d_out);
}